// Round 1
// baseline (84.034 us; speedup 1.0000x reference)
//
#include <hip/hip_runtime.h>

// Fused: channel-reduce (64ch -> 1 via 1x1 conv weights) at INPUT resolution,
// then bilinear x4 upsample (align_corners) + bias + ReLU.
// Linearity lets the reduction commute with the interpolation.
//
// x:      (4, 64, 96, 320)  f32
// weight: (1, 64, 1, 1)     f32
// bias:   (1,)              f32
// out:    (4, 1, 384, 1280) f32

#define TH 32      // output rows per block
#define TW 160     // output cols per block
#define NR_MAX 10  // max input rows needed: ceil(31*95/383)+2 = 10
#define NC_PAD 43  // max input cols needed: 42, padded to 43 (odd) for LDS banks

__global__ __launch_bounds__(256)
void UpsampleDepthOutputReLu_kernel(const float* __restrict__ x,
                                    const float* __restrict__ wgt,
                                    const float* __restrict__ bias,
                                    float* __restrict__ out)
{
    constexpr int C = 64, H = 96, W = 320, Ho = 384, Wo = 1280;
    const float RH = 95.0f / 383.0f;     // (H-1)/(Ho-1), f32 — matches JAX weak-type math
    const float RW = 319.0f / 1279.0f;   // (W-1)/(Wo-1)

    __shared__ float zs[NR_MAX * NC_PAD];
    __shared__ float ws[C];

    const int tid = threadIdx.x;
    const int b   = blockIdx.z;
    const int oh0 = blockIdx.y * TH;
    const int ow0 = blockIdx.x * TW;

    if (tid < C) ws[tid] = wgt[tid];

    // Input patch bounds for this tile (wave-uniform).
    const int i_lo  = min((int)((float)oh0 * RH), H - 2);
    const int i_hi  = min((int)((float)(oh0 + TH - 1) * RH), H - 2) + 1;
    const int nrows = i_hi - i_lo + 1;               // <= 10
    const int j_lo  = min((int)((float)ow0 * RW), W - 2);
    const int j_hi  = min((int)((float)(ow0 + TW - 1) * RW), W - 2) + 1;
    const int ncols = j_hi - j_lo + 1;               // <= 42

    __syncthreads();

    // Phase 1: channel-reduce the input patch into LDS.
    const int npatch = nrows * ncols;                // <= 420 -> <=2 iters/thread
    const float* xb = x + (size_t)b * C * H * W;
    for (int idx = tid; idx < npatch; idx += 256) {
        const int r = idx / ncols;
        const int c = idx - r * ncols;
        const float* p = xb + (size_t)(i_lo + r) * W + (j_lo + c);
        float acc = 0.f;
        #pragma unroll 16
        for (int ch = 0; ch < C; ++ch)
            acc += p[(size_t)ch * H * W] * ws[ch];
        zs[r * NC_PAD + c] = acc;
    }
    __syncthreads();

    // Phase 2: bilinear lerp from LDS, +bias, ReLU, float4 stores.
    const float bv = bias[0];
    float* ob = out + ((size_t)b * Ho + oh0) * Wo + ow0;
    #pragma unroll
    for (int k = 0; k < (TH * TW) / (256 * 4); ++k) {   // 5 iters
        const int lin  = (k * 256 + tid) * 4;
        const int oh_l = lin / TW;
        const int ow_l = lin - oh_l * TW;

        const float ph = (float)(oh0 + oh_l) * RH;
        const int   i0 = min((int)ph, H - 2);
        const float wy = ph - (float)i0;
        const int   r  = i0 - i_lo;

        float vals[4];
        #pragma unroll
        for (int j = 0; j < 4; ++j) {
            const int   ow = ow0 + ow_l + j;
            const float pw = (float)ow * RW;
            const int   j0 = min((int)pw, W - 2);
            const float wx = pw - (float)j0;
            const int   c  = j0 - j_lo;
            const float top = zs[r * NC_PAD + c]       * (1.f - wx) + zs[r * NC_PAD + c + 1]       * wx;
            const float bot = zs[(r + 1) * NC_PAD + c] * (1.f - wx) + zs[(r + 1) * NC_PAD + c + 1] * wx;
            const float v   = top * (1.f - wy) + bot * wy + bv;
            vals[j] = fmaxf(v, 0.f);
        }
        *(float4*)(ob + (size_t)oh_l * Wo + ow_l) =
            make_float4(vals[0], vals[1], vals[2], vals[3]);
    }
}

extern "C" void kernel_launch(void* const* d_in, const int* in_sizes, int n_in,
                              void* d_out, int out_size, void* d_ws, size_t ws_size,
                              hipStream_t stream) {
    const float* x    = (const float*)d_in[0];
    const float* wgt  = (const float*)d_in[1];
    const float* bias = (const float*)d_in[2];
    float* out = (float*)d_out;

    dim3 grid(1280 / TW, 384 / TH, 4);   // (8, 12, 4) = 384 blocks
    UpsampleDepthOutputReLu_kernel<<<grid, 256, 0, stream>>>(x, wgt, bias, out);
}

// Round 2
// 81.320 us; speedup vs baseline: 1.0334x; 1.0334x over previous
//
#include <hip/hip_runtime.h>

// Two-kernel split (linearity: 1x1-conv channel-reduce commutes with bilinear):
//   K1: z[b,h,w] = sum_c w[c] * x[b,c,h,w]     (31.5 MB read -> 0.49 MB write)
//   K2: out = relu(bilinear_x4_ac(z) + bias)   (0.49 MB read (L2) -> 7.9 MB write)
//
// x: (4,64,96,320) f32 | weight: (1,64,1,1) f32 | bias: (1,) f32
// out: (4,1,384,1280) f32 | z lives in d_ws (491,520 B)

constexpr int C = 64, H = 96, W = 320, HW = H * W;          // HW = 30720
constexpr int Ho = 384, Wo = 1280;
constexpr int HW4 = HW / 4;                                  // 7680 float4/image

// ---- K1: channel reduce. 4 lanes per output float4 (16 ch each) + butterfly.
__global__ __launch_bounds__(256)
void reduce_c_kernel(const float* __restrict__ x,
                     const float* __restrict__ wgt,
                     float* __restrict__ z)
{
    __shared__ float ws[C];
    const int tid = threadIdx.x;
    if (tid < C) ws[tid] = wgt[tid];
    __syncthreads();

    const int gt = blockIdx.x * 256 + tid;   // 480*256 = 122880 threads
    const int q  = gt >> 2;                  // float4 index into z (0..30719)
    const int lc = gt & 3;                   // channel group 0..3
    const int b  = q / HW4;
    const int s  = (q - b * HW4) * 4;        // spatial float offset within image

    const float* p = x + (size_t)b * C * HW + s;
    float4 acc = make_float4(0.f, 0.f, 0.f, 0.f);
    #pragma unroll
    for (int k = 0; k < 16; ++k) {
        const int ch = lc * 16 + k;
        const float4 v = *(const float4*)(p + (size_t)ch * HW);
        const float wv = ws[ch];
        acc.x += v.x * wv; acc.y += v.y * wv;
        acc.z += v.z * wv; acc.w += v.w * wv;
    }
    // reduce across the 4 channel-group lanes (xor 1, then xor 2)
    acc.x += __shfl_xor(acc.x, 1); acc.y += __shfl_xor(acc.y, 1);
    acc.z += __shfl_xor(acc.z, 1); acc.w += __shfl_xor(acc.w, 1);
    acc.x += __shfl_xor(acc.x, 2); acc.y += __shfl_xor(acc.y, 2);
    acc.z += __shfl_xor(acc.z, 2); acc.w += __shfl_xor(acc.w, 2);

    if (lc == 0) ((float4*)z)[q] = acc;
}

// ---- K2: bilinear x4 (align_corners) + bias + ReLU, float4 stores.
__global__ __launch_bounds__(256)
void upsample_kernel(const float* __restrict__ z,
                     const float* __restrict__ bias,
                     float* __restrict__ out)
{
    const float RH = 95.0f / 383.0f;     // (H-1)/(Ho-1) in f32, matches JAX
    const float RW = 319.0f / 1279.0f;   // (W-1)/(Wo-1)

    const int gt = blockIdx.x * 256 + threadIdx.x;  // 1920*256 = 491520 float4s
    const int o  = gt * 4;                           // flat float offset in out
    const int b  = o / (Ho * Wo);
    const int r  = o - b * (Ho * Wo);
    const int oh = r / Wo;
    const int ow = r - oh * Wo;                      // multiple of 4

    const float ph = (float)oh * RH;
    const int   i0 = min((int)ph, H - 2);
    const float wy = ph - (float)i0;

    const float* z0 = z + ((size_t)b * H + i0) * W;
    const float* z1 = z0 + W;
    const float bv = bias[0];

    float vals[4];
    #pragma unroll
    for (int j = 0; j < 4; ++j) {
        const float pw = (float)(ow + j) * RW;
        const int   j0 = min((int)pw, W - 2);
        const float wx = pw - (float)j0;
        const float top = z0[j0] * (1.f - wx) + z0[j0 + 1] * wx;
        const float bot = z1[j0] * (1.f - wx) + z1[j0 + 1] * wx;
        const float v   = top * (1.f - wy) + bot * wy + bv;
        vals[j] = fmaxf(v, 0.f);
    }
    ((float4*)out)[gt] = make_float4(vals[0], vals[1], vals[2], vals[3]);
}

extern "C" void kernel_launch(void* const* d_in, const int* in_sizes, int n_in,
                              void* d_out, int out_size, void* d_ws, size_t ws_size,
                              hipStream_t stream) {
    const float* x    = (const float*)d_in[0];
    const float* wgt  = (const float*)d_in[1];
    const float* bias = (const float*)d_in[2];
    float* out = (float*)d_out;
    float* z   = (float*)d_ws;   // 4*96*320 floats = 491,520 B << ws_size

    reduce_c_kernel<<<dim3((4 * HW4 * 4) / 256), 256, 0, stream>>>(x, wgt, z);
    upsample_kernel<<<dim3((4 * Ho * Wo / 4) / 256), 256, 0, stream>>>(z, bias, out);
}